// Round 11
// baseline (680.083 us; speedup 1.0000x reference)
//
#include <hip/hip_runtime.h>

// ConventionalGNN: 3x (GCNConv -> GraphNorm -> ReLU), N=100000 nodes, E=1.6M edges, D=128.
// Hs = dinv*h stored FP16 packed; AGG[n] = dinv[n]*(sum Hs[src] + Hs[n]), stored fp16.
// H and AGG are COLUMN-BLOCKED: 8 blocks x 16 cols (32B/row); block p -> XCD p (blockIdx&7),
// per-XCD gather working set = 3.2MB, L2-resident.
// QUAD-UNIFORM PADDED CSR: the 4 nodes of each aligned quad share one padded slot count
// (max of quad, +self, rounded to 8) -> gather nb is wave-uniform (SGPR), all pipeline
// guards are scalar branches, no per-batch clamps. Depth-4 named-register H pipeline.

#define EPS_GN 1e-5f

typedef __attribute__((ext_vector_type(8))) _Float16 f16x8;
typedef __attribute__((ext_vector_type(2))) _Float16 f16x2;
typedef __attribute__((ext_vector_type(4))) float f32x4;

template <typename T, typename U>
__device__ __forceinline__ T bc(U u) {
  return __builtin_bit_cast(T, u);
}
// pack 2 floats -> packed fp16 dword (RTZ, 1 instr)
__device__ __forceinline__ unsigned pkh(float x, float y) {
  return bc<unsigned>(__builtin_amdgcn_cvt_pkrtz(x, y));
}

// ---------------- CSR build ----------------

__global__ __launch_bounds__(256) void k_count_p(const int* __restrict__ dst,
                                                 int* __restrict__ cnt, int E, int N) {
  int p = blockIdx.x & 7;
  int lo = (int)((long long)N * p >> 3), hi = (int)((long long)N * (p + 1) >> 3);
  int stride = (gridDim.x >> 3) * 256;
  for (int e = (blockIdx.x >> 3) * 256 + threadIdx.x; e < E; e += stride) {
    int d = dst[e];
    if (d >= lo && d < hi) atomicAdd(&cnt[d], 1);
  }
}

// Scan of QUAD-UNIFORM padded slot counts: pc = (max(cnt[quad])+8)&~7 for all 4 nodes.
// Thread t handles the aligned quad [base, base+4) (N % 4 == 0).
__global__ __launch_bounds__(256) void k_scan1(const int* __restrict__ cnt,
                                               int* __restrict__ rs,
                                               int* __restrict__ bsum, int N) {
  __shared__ int s[256];
  int t = threadIdx.x;
  int base = blockIdx.x * 1024 + t * 4;
  bool valid = base < N;  // N%4==0 -> whole quad valid
  int c0 = valid ? cnt[base + 0] : 0;
  int c1 = valid ? cnt[base + 1] : 0;
  int c2 = valid ? cnt[base + 2] : 0;
  int c3 = valid ? cnt[base + 3] : 0;
  int mc = max(max(c0, c1), max(c2, c3));
  int pcq = valid ? ((mc + 8) & ~7) : 0;
  int tsum = pcq * 4;
  s[t] = tsum;
  __syncthreads();
  for (int off = 1; off < 256; off <<= 1) {
    int v = (t >= off) ? s[t - off] : 0;
    __syncthreads();
    s[t] += v;
    __syncthreads();
  }
  int excl = s[t] - tsum;
  if (t == 255) bsum[blockIdx.x] = s[255];
  if (valid) {
    rs[base + 0] = excl;
    rs[base + 1] = excl + pcq;
    rs[base + 2] = excl + 2 * pcq;
    rs[base + 3] = excl + 3 * pcq;
  }
}

__global__ __launch_bounds__(256) void k_scan2(const int* __restrict__ bsum,
                                               int* __restrict__ boff, int nblk) {
  __shared__ int s[256];
  int t = threadIdx.x;
  int v0 = (t < nblk) ? bsum[t] : 0;
  s[t] = v0;
  __syncthreads();
  for (int off = 1; off < 256; off <<= 1) {
    int v = (t >= off) ? s[t - off] : 0;
    __syncthreads();
    s[t] += v;
    __syncthreads();
  }
  if (t < nblk) boff[t] = s[t] - v0;
}

// Finalize: rs -> quad-padded slot offsets; cursor = rs+1; dinv; self slot (byte off i*32);
// pad slots [v+1+cnt, v+pc) = NB; zero-row N of Hcb; 1024-dword csrp tail = NB.
__global__ __launch_bounds__(256) void k_finalize(const int* __restrict__ cnt,
                                                  const int* __restrict__ boff,
                                                  int* __restrict__ rs,
                                                  int* __restrict__ cursor,
                                                  float* __restrict__ dinv,
                                                  unsigned* __restrict__ Hcb,
                                                  int* __restrict__ csrp, int N, int E,
                                                  int ROWS) {
  __shared__ int sTail;
  int i = blockIdx.x * 256 + threadIdx.x;
  int NB = N * 32;
  if (i < 64) Hcb[((size_t)(i >> 3) * ROWS + N) * 8 + (i & 7)] = 0u;
  if (i < N) {
    int qb = i & ~3;
    int mc = max(max(cnt[qb], cnt[qb + 1]), max(cnt[qb + 2], cnt[qb + 3]));
    int pc = (mc + 8) & ~7;
    int c = cnt[i];
    int v = rs[i] + boff[i >> 10];
    rs[i] = v;
    cursor[i] = v + 1;
    dinv[i] = rsqrtf((float)c + 1.0f);
    csrp[v] = i * 32;  // self slot (byte offset)
    for (int k = v + 1 + c; k < v + pc; ++k) csrp[k] = NB;  // pads -> zero row
    if (i == N - 1) {
      rs[N] = v + pc;
      sTail = v + pc;
    }
  }
  __syncthreads();
  if (blockIdx.x == gridDim.x - 1) {
    int base = sTail;
    for (int k = threadIdx.x; k < 1024; k += 256) csrp[base + k] = NB;
  }
}

__global__ __launch_bounds__(256) void k_fill_p(const int* __restrict__ src,
                                                const int* __restrict__ dst,
                                                int* __restrict__ cursor,
                                                int* __restrict__ csrp, int E, int N) {
  int p = blockIdx.x & 7;
  int lo = (int)((long long)N * p >> 3), hi = (int)((long long)N * (p + 1) >> 3);
  int stride = (gridDim.x >> 3) * 256;
  for (int e = (blockIdx.x >> 3) * 256 + threadIdx.x; e < E; e += stride) {
    int d = dst[e];
    if (d >= lo && d < hi) {
      int pos = atomicAdd(&cursor[d], 1);
      csrp[pos] = src[e] << 5;  // byte offset
    }
  }
}

// ---------------- Weight transpose (once per call) ----------------

// WbT[layer][n][k] = fp16(W12[layer][k][n]); output-coalesced.
__global__ __launch_bounds__(256) void k_wt(const float* __restrict__ W12,
                                            _Float16* __restrict__ WbT) {
  int o = blockIdx.x * 256 + threadIdx.x;  // [0, 2*16384)
  int layer = o >> 14, r = o & 16383;
  int n = r >> 7, k = r & 127;
  WbT[o] = (_Float16)W12[layer * 16384 + k * 128 + n];
}

// ---------------- Layer kernels ----------------

// Hs(fp16, col-blocked) = dinv * (X @ W0). 4 rows/block; thread = 1 row x 2 cols.
__global__ __launch_bounds__(256) void k_gemm0(const float* __restrict__ X,
                                               const float* __restrict__ W,
                                               const float* __restrict__ dinv,
                                               unsigned* __restrict__ Hcb, int N, int ROWS) {
  __shared__ float Ws[4 * 128];
  int t = threadIdx.x;
  if (t < 128) {
    Ws[t] = W[t];
    Ws[128 + t] = W[128 + t];
    Ws[256 + t] = W[256 + t];
    Ws[384 + t] = W[384 + t];
  }
  __syncthreads();
  int r = t >> 6, l = t & 63;
  int row = blockIdx.x * 4 + r;
  if (row >= N) return;
  float4 xv = ((const float4*)X)[row];
  float di = dinv[row];
  int c0 = 2 * l, c1 = 2 * l + 1;
  float v0 = xv.x * Ws[c0] + xv.y * Ws[128 + c0] + xv.z * Ws[256 + c0] + xv.w * Ws[384 + c0];
  float v1 = xv.x * Ws[c1] + xv.y * Ws[128 + c1] + xv.z * Ws[256 + c1] + xv.w * Ws[384 + c1];
  Hcb[((size_t)(l >> 3) * ROWS + row) * 8 + (l & 7)] = pkh(di * v0, di * v1);
}

// Hs(fp16, col-blocked) = dinv * (relu(norm(AGGcb)) @ W) via MFMA 16x16x32 f16.
__global__ __launch_bounds__(256, 4) void k_gemm_mfma(const unsigned* __restrict__ AGGcb,
                                                      const _Float16* __restrict__ WbT,
                                                      const float* __restrict__ stats,
                                                      const float* __restrict__ bias,
                                                      const float* __restrict__ gamma,
                                                      const float* __restrict__ beta,
                                                      const float* __restrict__ alpha,
                                                      const float* __restrict__ dinv,
                                                      unsigned* __restrict__ Hcb, int N,
                                                      int ROWS, float invN) {
  __shared__ float As[128], Bs[128];
  int t = threadIdx.x;
  if (t < 128) {
    float s1 = stats[t] * invN, s2 = stats[128 + t] * invN;
    float b = bias[t], a = alpha[t], g = gamma[t], be = beta[t];
    float mu = s1 + b;                     // mean of (agg + b)
    float E2 = s2 + 2.f * b * s1 + b * b;  // E[(agg+b)^2]
    float var = E2 - (2.f * a - a * a) * mu * mu;
    float A = g * rsqrtf(var + EPS_GN);
    As[t] = A;
    Bs[t] = be - A * a * mu + A * b;  // normed = A*agg + B
  }
  __syncthreads();
  int wv = t >> 6, l = t & 63;
  int r0 = blockIdx.x * 64 + wv * 16;
  if (r0 >= N) return;
  int m = l & 15, kb = l >> 4;

  f32x4 acc[8];
#pragma unroll
  for (int nt = 0; nt < 8; ++nt) acc[nt] = (f32x4){0.f, 0.f, 0.f, 0.f};

#pragma unroll
  for (int ks = 0; ks < 4; ++ks) {
    int k0 = ks * 32 + kb * 8;
    const uint4* pa = (const uint4*)(AGGcb + ((size_t)(2 * ks + (kb >> 1)) * ROWS + r0 + m) * 8 +
                                     (kb & 1) * 4);
    uint4 a_raw = pa[0];
    float4 A0 = *reinterpret_cast<const float4*>(&As[k0]);
    float4 A1 = *reinterpret_cast<const float4*>(&As[k0 + 4]);
    float4 B0 = *reinterpret_cast<const float4*>(&Bs[k0]);
    float4 B1 = *reinterpret_cast<const float4*>(&Bs[k0 + 4]);
    f16x8 bf[8];
#pragma unroll
    for (int nt = 0; nt < 8; ++nt)
      bf[nt] = *reinterpret_cast<const f16x8*>(WbT + (size_t)(nt * 16 + m) * 128 + k0);
    unsigned uu[4] = {a_raw.x, a_raw.y, a_raw.z, a_raw.w};
    float xr[8];
#pragma unroll
    for (int i = 0; i < 4; ++i) {
      f16x2 hp = bc<f16x2>(uu[i]);
      xr[2 * i] = (float)hp[0];
      xr[2 * i + 1] = (float)hp[1];
    }
    float Aa[8] = {A0.x, A0.y, A0.z, A0.w, A1.x, A1.y, A1.z, A1.w};
    float Bb[8] = {B0.x, B0.y, B0.z, B0.w, B1.x, B1.y, B1.z, B1.w};
    float xs[8];
#pragma unroll
    for (int j = 0; j < 8; ++j) {
      float v = fmaf(Aa[j], xr[j], Bb[j]);
      xs[j] = v > 0.f ? v : 0.f;
    }
    uint4 au;
    au.x = pkh(xs[0], xs[1]);
    au.y = pkh(xs[2], xs[3]);
    au.z = pkh(xs[4], xs[5]);
    au.w = pkh(xs[6], xs[7]);
    f16x8 af = bc<f16x8>(au);
#pragma unroll
    for (int nt = 0; nt < 8; ++nt)
      acc[nt] = __builtin_amdgcn_mfma_f32_16x16x32_f16(af, bf[nt], acc[nt], 0, 0, 0);
  }

  float dn[4];
#pragma unroll
  for (int r = 0; r < 4; ++r) dn[r] = dinv[r0 + kb * 4 + r];
  bool even = (l & 1) == 0;
#pragma unroll
  for (int nt = 0; nt < 8; ++nt) {
#pragma unroll
    for (int r = 0; r < 4; ++r) {
      float v = acc[nt][r] * dn[r];
      float pv = __shfl_xor(v, 1);
      if (even) {
        unsigned word = pkh(v, pv);
        Hcb[((size_t)nt * ROWS + r0 + kb * 4 + r) * 8 + (m >> 1)] = word;
      }
    }
  }
}

// Column-blocked gather v5: partition p = blockIdx&7 -> cols [16p,16p+16).
// Wave = aligned quad of 4 nodes (g) x 8 slots (e) x 2 half-rows (h); lane loads uint4.
// nb (padded batch count) is QUAD-UNIFORM -> SGPR -> all guards scalar; no per-lane clamps.
// Depth-4 named-register H pipeline (h0..h3), csr prefetched one unroll-iter ahead.
__global__ __launch_bounds__(256) void k_gather_cb(const unsigned* __restrict__ Hcb,
                                                   const int* __restrict__ rsp,
                                                   const int* __restrict__ csrp,
                                                   const float* __restrict__ dinv,
                                                   unsigned* __restrict__ AGGcb,
                                                   float* __restrict__ stats, int N, int ROWS) {
  int t = threadIdx.x;
  int wave = t >> 6, lane = t & 63;
  int g = lane >> 4, e = (lane >> 1) & 7, h = lane & 1;
  int p = blockIdx.x & 7;
  const unsigned char* HpB = (const unsigned char*)Hcb + (size_t)p * ROWS * 32;  // uniform
  uint4* Ap4 = (uint4*)(AGGcb + (size_t)p * ROWS * 8);
  int ho = h * 16;
  int q = blockIdx.x >> 3;
  int nstride = (gridDim.x >> 3) * 16;  // blocks/partition * 4 waves * 4 nodes
  float s1acc[8], s2acc[8];
#pragma unroll
  for (int i = 0; i < 8; ++i) s1acc[i] = s2acc[i] = 0.f;

  for (int n0 = (q * 4 + wave) * 4; n0 < N; n0 += nstride) {
    int n = n0 + g;  // aligned quad, N % 4 == 0
    int j0 = rsp[n];
    int nb = __builtin_amdgcn_readfirstlane((rsp[n + 1] - j0) >> 3);  // quad-uniform
    f16x2 acc[4];
#pragma unroll
    for (int i = 0; i < 4; ++i) acc[i] = (f16x2){(_Float16)0, (_Float16)0};

    const int* cp = csrp + j0 + e;  // lane slot pointer; batch b at cp[b*8]
    auto ldh = [&](int c) -> uint4 { return *(const uint4*)(HpB + (unsigned)(c + ho)); };

    // prologue: up to 4 H loads in flight + csr for batches 4..7
    uint4 h0 = ldh(cp[0]);
    uint4 h1 = {}, h2 = {}, h3 = {};
    if (nb > 1) h1 = ldh(cp[8]);
    if (nb > 2) h2 = ldh(cp[16]);
    if (nb > 3) h3 = ldh(cp[24]);
    int cA = 0, cB = 0, cC = 0, cD = 0;
    if (nb > 4) {
      cA = cp[32];
      cB = cp[40];
      cC = cp[48];
      cD = cp[56];
    }
    const int* cpn = cp + 64;  // csr for batches 8..11 on first refill

    for (int b = 0; b < nb; b += 4) {  // all guards wave-uniform (scalar)
      acc[0] += bc<f16x2>(h0.x);
      acc[1] += bc<f16x2>(h0.y);
      acc[2] += bc<f16x2>(h0.z);
      acc[3] += bc<f16x2>(h0.w);
      if (b + 4 < nb) h0 = ldh(cA);
      if (b + 1 < nb) {
        acc[0] += bc<f16x2>(h1.x);
        acc[1] += bc<f16x2>(h1.y);
        acc[2] += bc<f16x2>(h1.z);
        acc[3] += bc<f16x2>(h1.w);
        if (b + 5 < nb) h1 = ldh(cB);
      }
      if (b + 2 < nb) {
        acc[0] += bc<f16x2>(h2.x);
        acc[1] += bc<f16x2>(h2.y);
        acc[2] += bc<f16x2>(h2.z);
        acc[3] += bc<f16x2>(h2.w);
        if (b + 6 < nb) h2 = ldh(cC);
      }
      if (b + 3 < nb) {
        acc[0] += bc<f16x2>(h3.x);
        acc[1] += bc<f16x2>(h3.y);
        acc[2] += bc<f16x2>(h3.z);
        acc[3] += bc<f16x2>(h3.w);
        if (b + 7 < nb) h3 = ldh(cD);
      }
      if (b + 8 < nb) {
        cA = cpn[0];
        cB = cpn[8];
        cC = cpn[16];
        cD = cpn[24];
      }
      cpn += 32;
    }
    // reduce across the 8 edge-slots (lane bits 1..3), packed
#pragma unroll
    for (int i = 0; i < 4; ++i) {
      acc[i] += bc<f16x2>((unsigned)__shfl_xor(bc<int>(acc[i]), 2));
      acc[i] += bc<f16x2>((unsigned)__shfl_xor(bc<int>(acc[i]), 4));
      acc[i] += bc<f16x2>((unsigned)__shfl_xor(bc<int>(acc[i]), 8));
    }
    if (e == 0) {
      float dn = dinv[n];
      float v[8];
#pragma unroll
      for (int i = 0; i < 4; ++i) {
        v[2 * i] = (float)acc[i][0] * dn;
        v[2 * i + 1] = (float)acc[i][1] * dn;
      }
      uint4 wv;
      unsigned* wp = (unsigned*)&wv;
#pragma unroll
      for (int i = 0; i < 4; ++i) wp[i] = pkh(v[2 * i], v[2 * i + 1]);
      Ap4[(size_t)n * 2 + h] = wv;
#pragma unroll
      for (int i = 0; i < 8; ++i) {
        s1acc[i] += v[i];
        s2acc[i] = fmaf(v[i], v[i], s2acc[i]);
      }
    }
  }
  // stats: reduce across nodes/groups (lane bits 4,5); lanes 0 (h=0) and 1 (h=1) hold sums.
#pragma unroll
  for (int i = 0; i < 8; ++i) {
    s1acc[i] += __shfl_xor(s1acc[i], 16);
    s1acc[i] += __shfl_xor(s1acc[i], 32);
    s2acc[i] += __shfl_xor(s2acc[i], 16);
    s2acc[i] += __shfl_xor(s2acc[i], 32);
  }
  __shared__ float sh[4][32];
  if (lane < 2) {
#pragma unroll
    for (int i = 0; i < 8; ++i) {
      sh[wave][h * 8 + i] = s1acc[i];
      sh[wave][16 + h * 8 + i] = s2acc[i];
    }
  }
  __syncthreads();
  if (t < 32) {
    float v = sh[0][t] + sh[1][t] + sh[2][t] + sh[3][t];
    if (t < 16)
      atomicAdd(&stats[p * 16 + t], v);
    else
      atomicAdd(&stats[128 + p * 16 + (t - 16)], v);
  }
}

// Final standalone norm (layer 2): fp16 col-blocked AGG -> fp32 row-major d_out.
__global__ __launch_bounds__(256) void k_norm(const unsigned* __restrict__ AGGcb,
                                              const float* __restrict__ stats,
                                              const float* __restrict__ bias,
                                              const float* __restrict__ gamma,
                                              const float* __restrict__ beta,
                                              const float* __restrict__ alpha,
                                              float* __restrict__ OUT, int N, int ROWS,
                                              float invN) {
  int i = blockIdx.x * 256 + threadIdx.x;  // 4-col chunk index over row-major out
  if (i >= N * 32) return;
  int row = i >> 5, c4 = i & 31;
  int blk = c4 >> 2, off = (2 * c4) & 7;
  uint2 u = *(const uint2*)(AGGcb + ((size_t)blk * ROWS + row) * 8 + off);
  f16x2 p0 = bc<f16x2>(u.x), p1 = bc<f16x2>(u.y);
  float vv[4] = {(float)p0[0], (float)p0[1], (float)p1[0], (float)p1[1]};
  float ov[4];
#pragma unroll
  for (int j = 0; j < 4; ++j) {
    int c = c4 * 4 + j;
    float s1 = stats[c] * invN, s2 = stats[128 + c] * invN;
    float b = bias[c], a = alpha[c], g = gamma[c], be = beta[c];
    float mu = s1 + b;
    float E2 = s2 + 2.f * b * s1 + b * b;
    float var = E2 - (2.f * a - a * a) * mu * mu;
    float A = g * rsqrtf(var + EPS_GN);
    float B = be - A * a * mu + A * b;
    float o = fmaf(A, vv[j], B);
    ov[j] = o > 0.f ? o : 0.f;
  }
  ((float4*)OUT)[i] = make_float4(ov[0], ov[1], ov[2], ov[3]);
}

// ---------------- Launch ----------------

extern "C" void kernel_launch(void* const* d_in, const int* in_sizes, int n_in,
                              void* d_out, int out_size, void* d_ws, size_t ws_size,
                              hipStream_t stream) {
  const float* x = (const float*)d_in[0];
  const int* ei = (const int*)d_in[1];
  const float* W0 = (const float*)d_in[2];
  const float* b0 = (const float*)d_in[3];
  const float* W12 = (const float*)d_in[4];
  const float* b12 = (const float*)d_in[5];
  const float* gamma = (const float*)d_in[6];
  const float* beta = (const float*)d_in[7];
  const float* alpha = (const float*)d_in[8];
  float* out = (float*)d_out;

  int N = in_sizes[0] / 4;
  int E = in_sizes[1] / 2;
  int ROWS = N + 1;
  const int* srcArr = ei;
  const int* dstArr = ei + E;

  char* w = (char*)d_ws;
  auto alloc = [&](size_t bytes) {
    char* p = w;
    w += (bytes + 255) & ~(size_t)255;
    return p;
  };
  int* cnt = (int*)alloc((size_t)N * 4);
  float* stats = (float*)alloc(3 * 256 * 4);  // [layer][sum(128)|sumsq(128)] - adjacent to cnt
  int* rs = (int*)alloc(((size_t)N + 1) * 4);
  int* cursor = (int*)alloc((size_t)N * 4);
  int* bsum = (int*)alloc(512);
  int* boff = (int*)alloc(512);
  _Float16* WbT = (_Float16*)alloc(2 * 16384 * 2);  // fp16 W^T, both layers
  int* csrp = (int*)alloc(((size_t)E + 24 * (size_t)N + 2048) * 4);  // quad-padded CSR + tail
  float* dinv = (float*)alloc((size_t)N * 4);
  unsigned* Hcb = (unsigned*)alloc((size_t)ROWS * 64 * 4);    // fp16 Hs, col-blocked
  unsigned* AGGcb = (unsigned*)alloc((size_t)ROWS * 64 * 4);  // fp16 agg, col-blocked

  // zero cnt + all stats (contiguous region)
  size_t zlen = (size_t)((char*)stats - (char*)cnt) + 3 * 256 * 4;
  hipMemsetAsync(cnt, 0, zlen, stream);

  int nblk = (N + 1023) / 1024;
  k_wt<<<128, 256, 0, stream>>>(W12, WbT);
  k_count_p<<<2048, 256, 0, stream>>>(dstArr, cnt, E, N);
  k_scan1<<<nblk, 256, 0, stream>>>(cnt, rs, bsum, N);
  k_scan2<<<1, 256, 0, stream>>>(bsum, boff, nblk);
  k_finalize<<<(N + 255) / 256, 256, 0, stream>>>(cnt, boff, rs, cursor, dinv, Hcb, csrp, N, E,
                                                  ROWS);
  k_fill_p<<<2048, 256, 0, stream>>>(srcArr, dstArr, cursor, csrp, E, N);

  float invN = 1.0f / (float)N;
  int gGemm = (N + 63) / 64;

  // Layer 0
  k_gemm0<<<(N + 3) / 4, 256, 0, stream>>>(x, W0, dinv, Hcb, N, ROWS);
  k_gather_cb<<<2048, 256, 0, stream>>>(Hcb, rs, csrp, dinv, AGGcb, stats, N, ROWS);
  // Layer 1 (norm of layer 0 fused into A-fragment build)
  k_gemm_mfma<<<gGemm, 256, 0, stream>>>(AGGcb, WbT, stats, b0, gamma, beta, alpha, dinv, Hcb, N,
                                         ROWS, invN);
  k_gather_cb<<<2048, 256, 0, stream>>>(Hcb, rs, csrp, dinv, AGGcb, stats + 256, N, ROWS);
  // Layer 2
  k_gemm_mfma<<<gGemm, 256, 0, stream>>>(AGGcb, WbT + 16384, stats + 256, b12, gamma + 128,
                                         beta + 128, alpha + 128, dinv, Hcb, N, ROWS, invN);
  k_gather_cb<<<2048, 256, 0, stream>>>(Hcb, rs, csrp, dinv, AGGcb, stats + 512, N, ROWS);
  // Final norm -> out
  k_norm<<<(N * 32 + 255) / 256, 256, 0, stream>>>(AGGcb, stats + 512, b12 + 128, gamma + 256,
                                                   beta + 256, alpha + 256, out, N, ROWS, invN);
}

// Round 12
// 607.796 us; speedup vs baseline: 1.1189x; 1.1189x over previous
//
#include <hip/hip_runtime.h>

// ConventionalGNN: 3x (GCNConv -> GraphNorm -> ReLU), N=100000 nodes, E=1.6M edges, D=128.
// Hs = dinv*h stored FP16 packed; AGG[n] = dinv[n]*(sum Hs[src] + Hs[n]), stored fp16.
// H and AGG are COLUMN-BLOCKED: 8 blocks x 16 cols (32B/row); block p -> XCD p (blockIdx&7),
// per-XCD gather working set = 3.2MB, L2-resident.
// PADDED CSR (per-node, byte offsets, slot0=self, pads->zero row N). Gather v4 (round-10
// validated): 4 nodes x 8 slots x 2 halves, pk_add_f16 accumulate, csr 2 ahead, H ping-pong.
// Edge streaming in count/fill vectorized as int4 (4 edges/load).

#define EPS_GN 1e-5f

typedef __attribute__((ext_vector_type(8))) _Float16 f16x8;
typedef __attribute__((ext_vector_type(2))) _Float16 f16x2;
typedef __attribute__((ext_vector_type(4))) float f32x4;

template <typename T, typename U>
__device__ __forceinline__ T bc(U u) {
  return __builtin_bit_cast(T, u);
}
// pack 2 floats -> packed fp16 dword (RTZ, 1 instr)
__device__ __forceinline__ unsigned pkh(float x, float y) {
  return bc<unsigned>(__builtin_amdgcn_cvt_pkrtz(x, y));
}

// ---------------- CSR build ----------------

__global__ __launch_bounds__(256) void k_count_p(const int* __restrict__ dst,
                                                 int* __restrict__ cnt, int E, int N) {
  int p = blockIdx.x & 7;
  int lo = (int)((long long)N * p >> 3), hi = (int)((long long)N * (p + 1) >> 3);
  int nthr = (gridDim.x >> 3) * 256;
  int tid = (blockIdx.x >> 3) * 256 + threadIdx.x;
  const int4* d4 = (const int4*)dst;
  int E4 = E >> 2;
  for (int i = tid; i < E4; i += nthr) {
    int4 v = d4[i];
    if (v.x >= lo && v.x < hi) atomicAdd(&cnt[v.x], 1);
    if (v.y >= lo && v.y < hi) atomicAdd(&cnt[v.y], 1);
    if (v.z >= lo && v.z < hi) atomicAdd(&cnt[v.z], 1);
    if (v.w >= lo && v.w < hi) atomicAdd(&cnt[v.w], 1);
  }
  for (int e = E4 * 4 + tid; e < E; e += nthr) {
    int d = dst[e];
    if (d >= lo && d < hi) atomicAdd(&cnt[d], 1);
  }
}

// Scan of PADDED slot counts pc = (cnt+8)&~7 (self + edges + pad to 8).
__global__ __launch_bounds__(256) void k_scan1(const int* __restrict__ cnt,
                                               int* __restrict__ rs,
                                               int* __restrict__ bsum, int N) {
  __shared__ int s[256];
  int t = threadIdx.x;
  int base = blockIdx.x * 1024 + t * 4;
  int c0 = (base + 0 < N) ? ((cnt[base + 0] + 8) & ~7) : 0;
  int c1 = (base + 1 < N) ? ((cnt[base + 1] + 8) & ~7) : 0;
  int c2 = (base + 2 < N) ? ((cnt[base + 2] + 8) & ~7) : 0;
  int c3 = (base + 3 < N) ? ((cnt[base + 3] + 8) & ~7) : 0;
  int tsum = c0 + c1 + c2 + c3;
  s[t] = tsum;
  __syncthreads();
  for (int off = 1; off < 256; off <<= 1) {
    int v = (t >= off) ? s[t - off] : 0;
    __syncthreads();
    s[t] += v;
    __syncthreads();
  }
  int excl = s[t] - tsum;
  if (t == 255) bsum[blockIdx.x] = s[255];
  int e0 = excl, e1 = e0 + c0, e2 = e1 + c1, e3 = e2 + c2;
  if (base + 0 < N) rs[base + 0] = e0;
  if (base + 1 < N) rs[base + 1] = e1;
  if (base + 2 < N) rs[base + 2] = e2;
  if (base + 3 < N) rs[base + 3] = e3;
}

__global__ __launch_bounds__(256) void k_scan2(const int* __restrict__ bsum,
                                               int* __restrict__ boff, int nblk) {
  __shared__ int s[256];
  int t = threadIdx.x;
  int v0 = (t < nblk) ? bsum[t] : 0;
  s[t] = v0;
  __syncthreads();
  for (int off = 1; off < 256; off <<= 1) {
    int v = (t >= off) ? s[t - off] : 0;
    __syncthreads();
    s[t] += v;
    __syncthreads();
  }
  if (t < nblk) boff[t] = s[t] - v0;
}

// Finalize: rs -> padded slot offsets; cursor = rs+1; dinv; self slot (byte offset i*32);
// pad slots = NB; zero-row N of Hcb; 1024-dword csrp tail = NB (safe lookahead).
__global__ __launch_bounds__(256) void k_finalize(const int* __restrict__ cnt,
                                                  const int* __restrict__ boff,
                                                  int* __restrict__ rs,
                                                  int* __restrict__ cursor,
                                                  float* __restrict__ dinv,
                                                  unsigned* __restrict__ Hcb,
                                                  int* __restrict__ csrp, int N, int E,
                                                  int ROWS) {
  __shared__ int sTail;
  int i = blockIdx.x * 256 + threadIdx.x;
  int NB = N * 32;
  if (i < 64) Hcb[((size_t)(i >> 3) * ROWS + N) * 8 + (i & 7)] = 0u;
  if (i < N) {
    int v = rs[i] + boff[i >> 10];
    int c = cnt[i];
    int pc = (c + 8) & ~7;
    rs[i] = v;
    cursor[i] = v + 1;
    dinv[i] = rsqrtf((float)c + 1.0f);
    csrp[v] = i * 32;  // self slot (byte offset)
    for (int k = v + 1 + c; k < v + pc; ++k) csrp[k] = NB;  // pads -> zero row
    if (i == N - 1) {
      rs[N] = v + pc;
      sTail = v + pc;
    }
  }
  __syncthreads();
  if (blockIdx.x == gridDim.x - 1) {
    int base = sTail;
    for (int k = threadIdx.x; k < 1024; k += 256) csrp[base + k] = NB;
  }
}

__global__ __launch_bounds__(256) void k_fill_p(const int* __restrict__ src,
                                                const int* __restrict__ dst,
                                                int* __restrict__ cursor,
                                                int* __restrict__ csrp, int E, int N) {
  int p = blockIdx.x & 7;
  int lo = (int)((long long)N * p >> 3), hi = (int)((long long)N * (p + 1) >> 3);
  int nthr = (gridDim.x >> 3) * 256;
  int tid = (blockIdx.x >> 3) * 256 + threadIdx.x;
  const int4* d4 = (const int4*)dst;
  const int4* s4 = (const int4*)src;
  int E4 = E >> 2;
  for (int i = tid; i < E4; i += nthr) {
    int4 d = d4[i];
    int4 s = s4[i];
    if (d.x >= lo && d.x < hi) csrp[atomicAdd(&cursor[d.x], 1)] = s.x << 5;
    if (d.y >= lo && d.y < hi) csrp[atomicAdd(&cursor[d.y], 1)] = s.y << 5;
    if (d.z >= lo && d.z < hi) csrp[atomicAdd(&cursor[d.z], 1)] = s.z << 5;
    if (d.w >= lo && d.w < hi) csrp[atomicAdd(&cursor[d.w], 1)] = s.w << 5;
  }
  for (int e = E4 * 4 + tid; e < E; e += nthr) {
    int d = dst[e];
    if (d >= lo && d < hi) csrp[atomicAdd(&cursor[d], 1)] = src[e] << 5;
  }
}

// ---------------- Weight transpose (once per call) ----------------

// WbT[layer][n][k] = fp16(W12[layer][k][n]); output-coalesced.
__global__ __launch_bounds__(256) void k_wt(const float* __restrict__ W12,
                                            _Float16* __restrict__ WbT) {
  int o = blockIdx.x * 256 + threadIdx.x;  // [0, 2*16384)
  int layer = o >> 14, r = o & 16383;
  int n = r >> 7, k = r & 127;
  WbT[o] = (_Float16)W12[layer * 16384 + k * 128 + n];
}

// ---------------- Layer kernels ----------------

// Hs(fp16, col-blocked) = dinv * (X @ W0). 4 rows/block; thread = 1 row x 2 cols.
__global__ __launch_bounds__(256) void k_gemm0(const float* __restrict__ X,
                                               const float* __restrict__ W,
                                               const float* __restrict__ dinv,
                                               unsigned* __restrict__ Hcb, int N, int ROWS) {
  __shared__ float Ws[4 * 128];
  int t = threadIdx.x;
  if (t < 128) {
    Ws[t] = W[t];
    Ws[128 + t] = W[128 + t];
    Ws[256 + t] = W[256 + t];
    Ws[384 + t] = W[384 + t];
  }
  __syncthreads();
  int r = t >> 6, l = t & 63;
  int row = blockIdx.x * 4 + r;
  if (row >= N) return;
  float4 xv = ((const float4*)X)[row];
  float di = dinv[row];
  int c0 = 2 * l, c1 = 2 * l + 1;
  float v0 = xv.x * Ws[c0] + xv.y * Ws[128 + c0] + xv.z * Ws[256 + c0] + xv.w * Ws[384 + c0];
  float v1 = xv.x * Ws[c1] + xv.y * Ws[128 + c1] + xv.z * Ws[256 + c1] + xv.w * Ws[384 + c1];
  Hcb[((size_t)(l >> 3) * ROWS + row) * 8 + (l & 7)] = pkh(di * v0, di * v1);
}

// Hs(fp16, col-blocked) = dinv * (relu(norm(AGGcb)) @ W) via MFMA 16x16x32 f16.
__global__ __launch_bounds__(256, 4) void k_gemm_mfma(const unsigned* __restrict__ AGGcb,
                                                      const _Float16* __restrict__ WbT,
                                                      const float* __restrict__ stats,
                                                      const float* __restrict__ bias,
                                                      const float* __restrict__ gamma,
                                                      const float* __restrict__ beta,
                                                      const float* __restrict__ alpha,
                                                      const float* __restrict__ dinv,
                                                      unsigned* __restrict__ Hcb, int N,
                                                      int ROWS, float invN) {
  __shared__ float As[128], Bs[128];
  int t = threadIdx.x;
  if (t < 128) {
    float s1 = stats[t] * invN, s2 = stats[128 + t] * invN;
    float b = bias[t], a = alpha[t], g = gamma[t], be = beta[t];
    float mu = s1 + b;                     // mean of (agg + b)
    float E2 = s2 + 2.f * b * s1 + b * b;  // E[(agg+b)^2]
    float var = E2 - (2.f * a - a * a) * mu * mu;
    float A = g * rsqrtf(var + EPS_GN);
    As[t] = A;
    Bs[t] = be - A * a * mu + A * b;  // normed = A*agg + B
  }
  __syncthreads();
  int wv = t >> 6, l = t & 63;
  int r0 = blockIdx.x * 64 + wv * 16;
  if (r0 >= N) return;
  int m = l & 15, kb = l >> 4;

  f32x4 acc[8];
#pragma unroll
  for (int nt = 0; nt < 8; ++nt) acc[nt] = (f32x4){0.f, 0.f, 0.f, 0.f};

#pragma unroll
  for (int ks = 0; ks < 4; ++ks) {
    int k0 = ks * 32 + kb * 8;
    const uint4* pa = (const uint4*)(AGGcb + ((size_t)(2 * ks + (kb >> 1)) * ROWS + r0 + m) * 8 +
                                     (kb & 1) * 4);
    uint4 a_raw = pa[0];
    float4 A0 = *reinterpret_cast<const float4*>(&As[k0]);
    float4 A1 = *reinterpret_cast<const float4*>(&As[k0 + 4]);
    float4 B0 = *reinterpret_cast<const float4*>(&Bs[k0]);
    float4 B1 = *reinterpret_cast<const float4*>(&Bs[k0 + 4]);
    f16x8 bf[8];
#pragma unroll
    for (int nt = 0; nt < 8; ++nt)
      bf[nt] = *reinterpret_cast<const f16x8*>(WbT + (size_t)(nt * 16 + m) * 128 + k0);
    unsigned uu[4] = {a_raw.x, a_raw.y, a_raw.z, a_raw.w};
    float xr[8];
#pragma unroll
    for (int i = 0; i < 4; ++i) {
      f16x2 hp = bc<f16x2>(uu[i]);
      xr[2 * i] = (float)hp[0];
      xr[2 * i + 1] = (float)hp[1];
    }
    float Aa[8] = {A0.x, A0.y, A0.z, A0.w, A1.x, A1.y, A1.z, A1.w};
    float Bb[8] = {B0.x, B0.y, B0.z, B0.w, B1.x, B1.y, B1.z, B1.w};
    float xs[8];
#pragma unroll
    for (int j = 0; j < 8; ++j) {
      float v = fmaf(Aa[j], xr[j], Bb[j]);
      xs[j] = v > 0.f ? v : 0.f;
    }
    uint4 au;
    au.x = pkh(xs[0], xs[1]);
    au.y = pkh(xs[2], xs[3]);
    au.z = pkh(xs[4], xs[5]);
    au.w = pkh(xs[6], xs[7]);
    f16x8 af = bc<f16x8>(au);
#pragma unroll
    for (int nt = 0; nt < 8; ++nt)
      acc[nt] = __builtin_amdgcn_mfma_f32_16x16x32_f16(af, bf[nt], acc[nt], 0, 0, 0);
  }

  float dn[4];
#pragma unroll
  for (int r = 0; r < 4; ++r) dn[r] = dinv[r0 + kb * 4 + r];
  bool even = (l & 1) == 0;
#pragma unroll
  for (int nt = 0; nt < 8; ++nt) {
#pragma unroll
    for (int r = 0; r < 4; ++r) {
      float v = acc[nt][r] * dn[r];
      float pv = __shfl_xor(v, 1);
      if (even) {
        unsigned word = pkh(v, pv);
        Hcb[((size_t)nt * ROWS + r0 + kb * 4 + r) * 8 + (m >> 1)] = word;
      }
    }
  }
}

// Column-blocked gather v4 (round-10 validated): partition p = blockIdx&7 -> cols [16p,16p+16).
// Wave = 4 nodes (g) x 8 slots (e) x 2 half-rows (h); lane loads uint4 (16B = 8 fp16).
// csrp holds byte offsets; H address = uniform base + (off + h*16) voffset.
// Accumulate with v_pk_add_f16 (4/batch); csr 2 batches ahead; H ping-pong, unroll-2.
__global__ __launch_bounds__(256) void k_gather_cb(const unsigned* __restrict__ Hcb,
                                                   const int* __restrict__ rsp,
                                                   const int* __restrict__ csrp,
                                                   const float* __restrict__ dinv,
                                                   unsigned* __restrict__ AGGcb,
                                                   float* __restrict__ stats, int N, int ROWS) {
  int t = threadIdx.x;
  int wave = t >> 6, lane = t & 63;
  int g = lane >> 4, e = (lane >> 1) & 7, h = lane & 1;
  int p = blockIdx.x & 7;
  const unsigned char* HpB = (const unsigned char*)Hcb + (size_t)p * ROWS * 32;  // uniform
  uint4* Ap4 = (uint4*)(AGGcb + (size_t)p * ROWS * 8);
  int NB = N * 32;
  int ho = h * 16;
  int q = blockIdx.x >> 3;
  int nstride = (gridDim.x >> 3) * 16;  // blocks/partition * 4 waves * 4 nodes
  float s1acc[8], s2acc[8];
#pragma unroll
  for (int i = 0; i < 8; ++i) s1acc[i] = s2acc[i] = 0.f;

  for (int n0 = (q * 4 + wave) * 4; n0 < N; n0 += nstride) {
    int n = n0 + g;  // N % 4 == 0 -> n < N
    int j0 = rsp[n], j1 = rsp[n + 1];
    int nb = (j1 - j0) >> 3;  // padded batch count (>= 1)
    int ml = nb;
    ml = max(ml, __shfl_xor(ml, 16));
    ml = max(ml, __shfl_xor(ml, 32));  // wave-uniform batch count
    f16x2 acc[4];
#pragma unroll
    for (int i = 0; i < 4; ++i) acc[i] = (f16x2){(_Float16)0, (_Float16)0};

    const int* cp = csrp + j0 + e;  // lane slot pointer; batch b at cp[b*8]
    auto hload = [&](int c, int b) -> uint4 {
      int ce = (b < nb) ? c : NB;  // beyond own batches -> zero row
      return *(const uint4*)(HpB + (unsigned)(ce + ho));
    };
    int c0 = cp[0], c1 = cp[8];
    uint4 hA = hload(c0, 0);
    uint4 hB = hload(c1, 1);
    int c2 = cp[16], c3 = cp[24];
    const int* cpp = cp + 32;  // batch 4

    for (int b = 0; b < ml; b += 2) {
      acc[0] += bc<f16x2>(hA.x);
      acc[1] += bc<f16x2>(hA.y);
      acc[2] += bc<f16x2>(hA.z);
      acc[3] += bc<f16x2>(hA.w);
      hA = hload(c2, b + 2);
      c2 = cpp[0];
      if (b + 1 < ml) {  // wave-uniform (scalar) branch
        acc[0] += bc<f16x2>(hB.x);
        acc[1] += bc<f16x2>(hB.y);
        acc[2] += bc<f16x2>(hB.z);
        acc[3] += bc<f16x2>(hB.w);
        hB = hload(c3, b + 3);
        c3 = cpp[8];
      }
      cpp += 16;
    }
    // reduce across the 8 edge-slots (lane bits 1..3), packed
#pragma unroll
    for (int i = 0; i < 4; ++i) {
      acc[i] += bc<f16x2>((unsigned)__shfl_xor(bc<int>(acc[i]), 2));
      acc[i] += bc<f16x2>((unsigned)__shfl_xor(bc<int>(acc[i]), 4));
      acc[i] += bc<f16x2>((unsigned)__shfl_xor(bc<int>(acc[i]), 8));
    }
    if (e == 0) {
      float dn = dinv[n];
      float v[8];
#pragma unroll
      for (int i = 0; i < 4; ++i) {
        v[2 * i] = (float)acc[i][0] * dn;
        v[2 * i + 1] = (float)acc[i][1] * dn;
      }
      uint4 wv;
      unsigned* wp = (unsigned*)&wv;
#pragma unroll
      for (int i = 0; i < 4; ++i) wp[i] = pkh(v[2 * i], v[2 * i + 1]);
      Ap4[(size_t)n * 2 + h] = wv;
#pragma unroll
      for (int i = 0; i < 8; ++i) {
        s1acc[i] += v[i];
        s2acc[i] = fmaf(v[i], v[i], s2acc[i]);
      }
    }
  }
  // stats: reduce across nodes/groups (lane bits 4,5); lanes 0 (h=0) and 1 (h=1) hold sums.
#pragma unroll
  for (int i = 0; i < 8; ++i) {
    s1acc[i] += __shfl_xor(s1acc[i], 16);
    s1acc[i] += __shfl_xor(s1acc[i], 32);
    s2acc[i] += __shfl_xor(s2acc[i], 16);
    s2acc[i] += __shfl_xor(s2acc[i], 32);
  }
  __shared__ float sh[4][32];
  if (lane < 2) {
#pragma unroll
    for (int i = 0; i < 8; ++i) {
      sh[wave][h * 8 + i] = s1acc[i];
      sh[wave][16 + h * 8 + i] = s2acc[i];
    }
  }
  __syncthreads();
  if (t < 32) {
    float v = sh[0][t] + sh[1][t] + sh[2][t] + sh[3][t];
    if (t < 16)
      atomicAdd(&stats[p * 16 + t], v);
    else
      atomicAdd(&stats[128 + p * 16 + (t - 16)], v);
  }
}

// Final standalone norm (layer 2): fp16 col-blocked AGG -> fp32 row-major d_out.
__global__ __launch_bounds__(256) void k_norm(const unsigned* __restrict__ AGGcb,
                                              const float* __restrict__ stats,
                                              const float* __restrict__ bias,
                                              const float* __restrict__ gamma,
                                              const float* __restrict__ beta,
                                              const float* __restrict__ alpha,
                                              float* __restrict__ OUT, int N, int ROWS,
                                              float invN) {
  int i = blockIdx.x * 256 + threadIdx.x;  // 4-col chunk index over row-major out
  if (i >= N * 32) return;
  int row = i >> 5, c4 = i & 31;
  int blk = c4 >> 2, off = (2 * c4) & 7;
  uint2 u = *(const uint2*)(AGGcb + ((size_t)blk * ROWS + row) * 8 + off);
  f16x2 p0 = bc<f16x2>(u.x), p1 = bc<f16x2>(u.y);
  float vv[4] = {(float)p0[0], (float)p0[1], (float)p1[0], (float)p1[1]};
  float ov[4];
#pragma unroll
  for (int j = 0; j < 4; ++j) {
    int c = c4 * 4 + j;
    float s1 = stats[c] * invN, s2 = stats[128 + c] * invN;
    float b = bias[c], a = alpha[c], g = gamma[c], be = beta[c];
    float mu = s1 + b;
    float E2 = s2 + 2.f * b * s1 + b * b;
    float var = E2 - (2.f * a - a * a) * mu * mu;
    float A = g * rsqrtf(var + EPS_GN);
    float B = be - A * a * mu + A * b;
    float o = fmaf(A, vv[j], B);
    ov[j] = o > 0.f ? o : 0.f;
  }
  ((float4*)OUT)[i] = make_float4(ov[0], ov[1], ov[2], ov[3]);
}

// ---------------- Launch ----------------

extern "C" void kernel_launch(void* const* d_in, const int* in_sizes, int n_in,
                              void* d_out, int out_size, void* d_ws, size_t ws_size,
                              hipStream_t stream) {
  const float* x = (const float*)d_in[0];
  const int* ei = (const int*)d_in[1];
  const float* W0 = (const float*)d_in[2];
  const float* b0 = (const float*)d_in[3];
  const float* W12 = (const float*)d_in[4];
  const float* b12 = (const float*)d_in[5];
  const float* gamma = (const float*)d_in[6];
  const float* beta = (const float*)d_in[7];
  const float* alpha = (const float*)d_in[8];
  float* out = (float*)d_out;

  int N = in_sizes[0] / 4;
  int E = in_sizes[1] / 2;
  int ROWS = N + 1;
  const int* srcArr = ei;
  const int* dstArr = ei + E;

  char* w = (char*)d_ws;
  auto alloc = [&](size_t bytes) {
    char* p = w;
    w += (bytes + 255) & ~(size_t)255;
    return p;
  };
  int* cnt = (int*)alloc((size_t)N * 4);
  float* stats = (float*)alloc(3 * 256 * 4);  // [layer][sum(128)|sumsq(128)] - adjacent to cnt
  int* rs = (int*)alloc(((size_t)N + 1) * 4);
  int* cursor = (int*)alloc((size_t)N * 4);
  int* bsum = (int*)alloc(512);
  int* boff = (int*)alloc(512);
  _Float16* WbT = (_Float16*)alloc(2 * 16384 * 2);                  // fp16 W^T, both layers
  int* csrp = (int*)alloc(((size_t)E + 8 * (size_t)N + 2048) * 4);  // padded CSR + tail
  float* dinv = (float*)alloc((size_t)N * 4);
  unsigned* Hcb = (unsigned*)alloc((size_t)ROWS * 64 * 4);    // fp16 Hs, col-blocked
  unsigned* AGGcb = (unsigned*)alloc((size_t)ROWS * 64 * 4);  // fp16 agg, col-blocked

  // zero cnt + all stats (contiguous region)
  size_t zlen = (size_t)((char*)stats - (char*)cnt) + 3 * 256 * 4;
  hipMemsetAsync(cnt, 0, zlen, stream);

  int nblk = (N + 1023) / 1024;
  k_wt<<<128, 256, 0, stream>>>(W12, WbT);
  k_count_p<<<2048, 256, 0, stream>>>(dstArr, cnt, E, N);
  k_scan1<<<nblk, 256, 0, stream>>>(cnt, rs, bsum, N);
  k_scan2<<<1, 256, 0, stream>>>(bsum, boff, nblk);
  k_finalize<<<(N + 255) / 256, 256, 0, stream>>>(cnt, boff, rs, cursor, dinv, Hcb, csrp, N, E,
                                                  ROWS);
  k_fill_p<<<2048, 256, 0, stream>>>(srcArr, dstArr, cursor, csrp, E, N);

  float invN = 1.0f / (float)N;
  int gGemm = (N + 63) / 64;

  // Layer 0
  k_gemm0<<<(N + 3) / 4, 256, 0, stream>>>(x, W0, dinv, Hcb, N, ROWS);
  k_gather_cb<<<2048, 256, 0, stream>>>(Hcb, rs, csrp, dinv, AGGcb, stats, N, ROWS);
  // Layer 1 (norm of layer 0 fused into A-fragment build)
  k_gemm_mfma<<<gGemm, 256, 0, stream>>>(AGGcb, WbT, stats, b0, gamma, beta, alpha, dinv, Hcb, N,
                                         ROWS, invN);
  k_gather_cb<<<2048, 256, 0, stream>>>(Hcb, rs, csrp, dinv, AGGcb, stats + 256, N, ROWS);
  // Layer 2
  k_gemm_mfma<<<gGemm, 256, 0, stream>>>(AGGcb, WbT + 16384, stats + 256, b12, gamma + 128,
                                         beta + 128, alpha + 128, dinv, Hcb, N, ROWS, invN);
  k_gather_cb<<<2048, 256, 0, stream>>>(Hcb, rs, csrp, dinv, AGGcb, stats + 512, N, ROWS);
  // Final norm -> out
  k_norm<<<(N * 32 + 255) / 256, 256, 0, stream>>>(AGGcb, stats + 512, b12 + 128, gamma + 256,
                                                   beta + 256, alpha + 256, out, N, ROWS, invN);
}